// Round 1
// baseline (216.452 us; speedup 1.0000x reference)
//
#include <hip/hip_runtime.h>
#include <cmath>

typedef _Float16 f16;
typedef _Float16 f16x8 __attribute__((ext_vector_type(8)));
typedef _Float16 f16x2 __attribute__((ext_vector_type(2)));
typedef float    f32x4 __attribute__((ext_vector_type(4)));
typedef unsigned short u16;
typedef unsigned int   u32;
typedef u16 us8 __attribute__((ext_vector_type(8)));
typedef u16 us4 __attribute__((ext_vector_type(4)));

#define MFMA16(a, b, c) __builtin_amdgcn_mfma_f32_16x16x32_f16((a), (b), (c), 0, 0, 0)

// ---------------- elementwise f32 -> f16 cast (8 elems / thread) ----------------
__global__ void castk(const float* __restrict__ src, f16* __restrict__ dst, int n8) {
    int i = blockIdx.x * 256 + threadIdx.x;
    if (i >= n8) return;
    const float4* s = (const float4*)src + (size_t)i * 2;
    float4 a = s[0], b = s[1];
    union { f16 h[8]; us8 v; } o;
    o.h[0] = (f16)a.x; o.h[1] = (f16)a.y; o.h[2] = (f16)a.z; o.h[3] = (f16)a.w;
    o.h[4] = (f16)b.x; o.h[5] = (f16)b.y; o.h[6] = (f16)b.z; o.h[7] = (f16)b.w;
    *(us8*)&dst[(size_t)i * 8] = o.v;
}

// ---------------- per-batch transpose+cast: O[b][s][h] f32 -> OT[b][h][s] f16 ----
__global__ void transpose_cast(const float* __restrict__ O, f16* __restrict__ OT) {
    __shared__ f16 tbuf[64][68];
    int bid = blockIdx.x;
    int b = bid >> 8, t = bid & 255;
    int s0 = (t & 31) * 64, h0 = (t >> 5) * 64;
    const float* Ob = O + (size_t)b * 2048 * 512;
    f16* OTb = OT + (size_t)b * 512 * 2048;
    int tid = threadIdx.x;
    int rr = tid >> 4, cc = (tid & 15) * 4;
#pragma unroll
    for (int i = 0; i < 4; ++i) {
        int r = rr + 16 * i;
        float4 v = *(const float4*)&Ob[(size_t)(s0 + r) * 512 + h0 + cc];
        tbuf[r][cc + 0] = (f16)v.x; tbuf[r][cc + 1] = (f16)v.y;
        tbuf[r][cc + 2] = (f16)v.z; tbuf[r][cc + 3] = (f16)v.w;
    }
    __syncthreads();
#pragma unroll
    for (int i = 0; i < 4; ++i) {
        int hr = rr + 16 * i;
        union { f16 h[4]; us4 v; } pk;
        pk.h[0] = tbuf[cc + 0][hr]; pk.h[1] = tbuf[cc + 1][hr];
        pk.h[2] = tbuf[cc + 2][hr]; pk.h[3] = tbuf[cc + 3][hr];
        *(us4*)&OTb[(size_t)(h0 + hr) * 2048 + s0 + cc] = pk.v;
    }
}

// ---------------- GEMM1: Qf16 = tanh(Of16 * Wf16^T + bias) ----------------------
// M=16384, N=512, K=512. 128x128 tile, BK=32, 4 waves of 64x64.
__global__ __launch_bounds__(256) void gemm1(const f16* __restrict__ A,
                                             const f16* __restrict__ W,
                                             const float* __restrict__ bias,
                                             f16* __restrict__ Qo) {
    __shared__ f16 lA[128 * 32];
    __shared__ f16 lB[128 * 32];
    const int tid = threadIdx.x;
    const int lane = tid & 63, w = tid >> 6;
    const int wm = w >> 1, wn = w & 1;
    const int bm = blockIdx.x >> 2, bn = blockIdx.x & 3;
    const int r0 = bm * 128, c0 = bn * 128;
    const int l15 = lane & 15, g = lane >> 4;
    f32x4 acc[4][4] = {};
    for (int kt = 0; kt < 16; ++kt) {
        int k0 = kt * 32;
        __syncthreads();
#pragma unroll
        for (int i = 0; i < 2; ++i) {
            int slot = i * 256 + tid;
            int row = slot >> 2, oct = slot & 3;
            int soct = oct ^ (row & 3);
            *(us8*)&lA[slot * 8] = *(const us8*)&A[(size_t)(r0 + row) * 512 + k0 + soct * 8];
            *(us8*)&lB[slot * 8] = *(const us8*)&W[(size_t)(c0 + row) * 512 + k0 + soct * 8];
        }
        __syncthreads();
        f16x8 af[4], bf[4];
#pragma unroll
        for (int mf = 0; mf < 4; ++mf) {
            int row = 64 * wm + 16 * mf + l15;
            int oct = g ^ (row & 3);
            af[mf] = *(const f16x8*)&lA[(row * 4 + oct) * 8];
        }
#pragma unroll
        for (int nf = 0; nf < 4; ++nf) {
            int row = 64 * wn + 16 * nf + l15;
            int oct = g ^ (row & 3);
            bf[nf] = *(const f16x8*)&lB[(row * 4 + oct) * 8];
        }
#pragma unroll
        for (int mf = 0; mf < 4; ++mf)
#pragma unroll
            for (int nf = 0; nf < 4; ++nf)
                acc[mf][nf] = MFMA16(af[mf], bf[nf], acc[mf][nf]);
    }
    // epilogue: tanh(acc + bias), store f16
    float bv[4];
#pragma unroll
    for (int nf = 0; nf < 4; ++nf) bv[nf] = bias[c0 + 64 * wn + 16 * nf + l15];
#pragma unroll
    for (int mf = 0; mf < 4; ++mf) {
#pragma unroll
        for (int nf = 0; nf < 4; ++nf) {
#pragma unroll
            for (int r = 0; r < 4; ++r) {
                float y = tanhf(acc[mf][nf][r] + bv[nf]);
                int row = r0 + 64 * wm + 16 * mf + 4 * g + r;
                int col = c0 + 64 * wn + 16 * nf + l15;
                Qo[(size_t)row * 512 + col] = (f16)y;
            }
        }
    }
}

// ---------------- fused attention -----------------------------------------------
// Grid: 256 blocks (b = blk>>5, qtile = blk&31), 256 threads (4 waves x 16 q-cols).
// S^T = K * Q^T via MFMA (softmax state at lane&15 = q), PV computes D[h][q].
__global__ __launch_bounds__(256, 1) void attn(const f16* __restrict__ Qf,
                                               const f16* __restrict__ Of,
                                               const f16* __restrict__ OfT,
                                               float* __restrict__ Out) {
    __shared__ __align__(16) char smem[65536];
    f16* lK = (f16*)smem;            // [32 t][64 oct ^ (t&7)]  32 KB
    f16* lV = (f16*)(smem + 32768);  // [512 h][4 oct ^ (h&3)]  32 KB
    const int tid = threadIdx.x;
    const int lane = tid & 63, w = tid >> 6;
    const int l15 = lane & 15, g = lane >> 4;
    const int b = blockIdx.x >> 5, qt = blockIdx.x & 31;
    const int q0 = qt * 64;
    const f16* Ob  = Of  + (size_t)b * 2048 * 512;
    const f16* OTb = OfT + (size_t)b * 512 * 2048;

    // Q B-fragments in registers: q = q0 + 16w + l15, k = 32ks + 8g + j
    f16x8 qf[16];
    const f16* qrow = Qf + ((size_t)b * 2048 + q0 + 16 * w + l15) * 512;
#pragma unroll
    for (int ks = 0; ks < 16; ++ks) qf[ks] = *(const f16x8*)&qrow[ks * 32 + g * 8];

    float m = -INFINITY, lsum = 0.f;
    f32x4 acc[32] = {};

    // bpermute source addresses for P repack
    const int addrA = 4 * (32 * (g & 1) + l15);
    const int addrB = addrA + 64;

    for (int kt = 0; kt < 64; ++kt) {
        const int t0 = kt * 32;
        __syncthreads();
        // stage K tile [32][512] (swizzled octets)
#pragma unroll
        for (int i = 0; i < 8; ++i) {
            int slot = i * 256 + tid;
            int t = slot >> 6, oct = slot & 63;
            int soct = oct ^ (t & 7);
            *(us8*)&lK[slot * 8] = *(const us8*)&Ob[(size_t)(t0 + t) * 512 + soct * 8];
        }
        // stage V^T tile [512][32] (swizzled octets)
#pragma unroll
        for (int i = 0; i < 8; ++i) {
            int slot = i * 256 + tid;
            int h = slot >> 2, oct = slot & 3;
            int soct = oct ^ (h & 3);
            *(us8*)&lV[slot * 8] = *(const us8*)&OTb[(size_t)h * 2048 + t0 + soct * 8];
        }
        __syncthreads();

        // QK^T: S^T[t][q], t in tile (32), q = wave's 16 cols
        f32x4 sa[2] = {};
#pragma unroll
        for (int ks = 0; ks < 16; ++ks) {
#pragma unroll
            for (int mf = 0; mf < 2; ++mf) {
                int t = 16 * mf + l15;
                int oct = (4 * ks + g) ^ (t & 7);
                f16x8 kf = *(const f16x8*)&lK[(t * 64 + oct) * 8];
                sa[mf] = MFMA16(kf, qf[ks], sa[mf]);
            }
        }

        // online softmax over t (column q = l15); defer-max THR=8
        float tmax = -INFINITY;
#pragma unroll
        for (int mf = 0; mf < 2; ++mf)
#pragma unroll
            for (int r = 0; r < 4; ++r) tmax = fmaxf(tmax, sa[mf][r]);
        tmax = fmaxf(tmax, __shfl_xor(tmax, 16));
        tmax = fmaxf(tmax, __shfl_xor(tmax, 32));
        if (__any(tmax > m + 8.0f)) {
            float mnew = fmaxf(m, tmax);
            float corr = __expf(m - mnew);
            m = mnew;
            lsum *= corr;
#pragma unroll
            for (int hf = 0; hf < 32; ++hf) acc[hf] *= corr;
        }
        float p[2][4];
        float ps = 0.f;
#pragma unroll
        for (int mf = 0; mf < 2; ++mf)
#pragma unroll
            for (int r = 0; r < 4; ++r) { p[mf][r] = __expf(sa[mf][r] - m); ps += p[mf][r]; }
        ps += __shfl_xor(ps, 16);
        ps += __shfl_xor(ps, 32);
        lsum += ps;

        // pack P to f16 words: Wd[mf][c] = (p[mf][2c], p[mf][2c+1])
        u32 Wd[2][2];
#pragma unroll
        for (int mf = 0; mf < 2; ++mf)
#pragma unroll
            for (int c = 0; c < 2; ++c) {
                union { f16 h[2]; u32 u; } x;
                x.h[0] = (f16)p[mf][2 * c]; x.h[1] = (f16)p[mf][2 * c + 1];
                Wd[mf][c] = x.u;
            }
        // repack via bpermute: B-frag word p: mf = g>>1, c = p&1,
        // srclane = 32*(g&1) + 16*(p>>1) + l15
        u32 word[4];
#pragma unroll
        for (int pp = 0; pp < 4; ++pp) {
            int adr = (pp >> 1) ? addrB : addrA;
            int w0 = __builtin_amdgcn_ds_bpermute(adr, (int)Wd[0][pp & 1]);
            int w1 = __builtin_amdgcn_ds_bpermute(adr, (int)Wd[1][pp & 1]);
            word[pp] = (lane >= 32) ? (u32)w1 : (u32)w0;
        }
        union { u32 u[4]; f16x8 v; } pkk;
        pkk.u[0] = word[0]; pkk.u[1] = word[1]; pkk.u[2] = word[2]; pkk.u[3] = word[3];
        f16x8 pfrag = pkk.v;

        // PV: D[h][q] += V^T[h][t] * P[q][t]
#pragma unroll
        for (int hf = 0; hf < 32; ++hf) {
            int h = 16 * hf + l15;
            int oct = g ^ (h & 3);
            f16x8 vf = *(const f16x8*)&lV[(h * 4 + oct) * 8];
            acc[hf] = MFMA16(vf, pfrag, acc[hf]);
        }
    }

    // epilogue: divide by lsum, transpose via LDS (2 halves of 256 h), store f32
    float inv = 1.0f / lsum;
#pragma unroll
    for (int hf = 0; hf < 32; ++hf) acc[hf] *= inv;

    float* lf = (float*)smem;  // [64 q][256 h] f32, h swizzled by ((q&7)<<2)
    const int q = 16 * w + l15;
#pragma unroll
    for (int half = 0; half < 2; ++half) {
        __syncthreads();
#pragma unroll
        for (int hfi = 0; hfi < 16; ++hfi) {
            int hf = 16 * half + hfi;
#pragma unroll
            for (int r = 0; r < 4; ++r) {
                int h = 16 * hf + 4 * g + r - half * 256;  // 0..255
                int hh = h ^ ((q & 7) << 2);
                lf[q * 256 + hh] = acc[hf][r];
            }
        }
        __syncthreads();
        int qr = tid >> 2;
        int c = tid & 3;
#pragma unroll
        for (int j = 0; j < 16; ++j) {
            int k4 = c + 4 * j;                    // quad index 0..63
            int hs = 4 * (k4 ^ (qr & 7));          // swizzled quad offset
            float4 vv = *(const float4*)&lf[qr * 256 + hs];
            *(float4*)&Out[((size_t)b * 2048 + q0 + qr) * 512 + half * 256 + 4 * k4] = vv;
        }
    }
}

extern "C" void kernel_launch(void* const* d_in, const int* in_sizes, int n_in,
                              void* d_out, int out_size, void* d_ws, size_t ws_size,
                              hipStream_t stream) {
    const float* O  = (const float*)d_in[0];
    const float* Ww = (const float*)d_in[1];
    const float* Wb = (const float*)d_in[2];
    float* Out = (float*)d_out;
    char* ws = (char*)d_ws;
    f16* Of16 = (f16*)ws;                           // 16 MB
    f16* OT   = (f16*)(ws + ((size_t)16 << 20));    // 16 MB
    f16* Qf   = (f16*)(ws + ((size_t)32 << 20));    // 16 MB
    f16* Wf   = (f16*)(ws + ((size_t)48 << 20));    // 512 KB

    castk<<<4096, 256, 0, stream>>>(O, Of16, 1048576);
    castk<<<128, 256, 0, stream>>>(Ww, Wf, 32768);
    transpose_cast<<<2048, 256, 0, stream>>>(O, OT);
    gemm1<<<512, 256, 0, stream>>>(Of16, Wf, Wb, Qf);
    attn<<<256, 256, 0, stream>>>(Qf, Of16, OT, Out);
}

// Round 2
// 209.645 us; speedup vs baseline: 1.0325x; 1.0325x over previous
//
#include <hip/hip_runtime.h>
#include <cmath>

typedef _Float16 f16;
typedef _Float16 f16x8 __attribute__((ext_vector_type(8)));
typedef float    f32x4 __attribute__((ext_vector_type(4)));
typedef unsigned short u16;
typedef unsigned int   u32;
typedef u16 us8 __attribute__((ext_vector_type(8)));
typedef u16 us4 __attribute__((ext_vector_type(4)));

#define MFMA16(a, b, c) __builtin_amdgcn_mfma_f32_16x16x32_f16((a), (b), (c), 0, 0, 0)

__device__ __forceinline__ void gload_lds16(const void* g, void* l) {
    __builtin_amdgcn_global_load_lds((const __attribute__((address_space(1))) void*)g,
                                     (__attribute__((address_space(3))) void*)l, 16, 0, 0);
}

// ---------------- elementwise f32 -> f16 cast (8 elems / thread) ----------------
__global__ void castk(const float* __restrict__ src, f16* __restrict__ dst, int n8) {
    int i = blockIdx.x * 256 + threadIdx.x;
    if (i >= n8) return;
    const float4* s = (const float4*)src + (size_t)i * 2;
    float4 a = s[0], b = s[1];
    union { f16 h[8]; us8 v; } o;
    o.h[0] = (f16)a.x; o.h[1] = (f16)a.y; o.h[2] = (f16)a.z; o.h[3] = (f16)a.w;
    o.h[4] = (f16)b.x; o.h[5] = (f16)b.y; o.h[6] = (f16)b.z; o.h[7] = (f16)b.w;
    *(us8*)&dst[(size_t)i * 8] = o.v;
}

// ---------------- per-batch transpose+cast: O[b][s][h] f32 -> OT[b][h][s] f16 ----
__global__ void transpose_cast(const float* __restrict__ O, f16* __restrict__ OT) {
    __shared__ f16 tbuf[64][68];
    int bid = blockIdx.x;
    int b = bid >> 8, t = bid & 255;
    int s0 = (t & 31) * 64, h0 = (t >> 5) * 64;
    const float* Ob = O + (size_t)b * 2048 * 512;
    f16* OTb = OT + (size_t)b * 512 * 2048;
    int tid = threadIdx.x;
    int rr = tid >> 4, cc = (tid & 15) * 4;
#pragma unroll
    for (int i = 0; i < 4; ++i) {
        int r = rr + 16 * i;
        float4 v = *(const float4*)&Ob[(size_t)(s0 + r) * 512 + h0 + cc];
        tbuf[r][cc + 0] = (f16)v.x; tbuf[r][cc + 1] = (f16)v.y;
        tbuf[r][cc + 2] = (f16)v.z; tbuf[r][cc + 3] = (f16)v.w;
    }
    __syncthreads();
#pragma unroll
    for (int i = 0; i < 4; ++i) {
        int hr = rr + 16 * i;
        union { f16 h[4]; us4 v; } pk;
        pk.h[0] = tbuf[cc + 0][hr]; pk.h[1] = tbuf[cc + 1][hr];
        pk.h[2] = tbuf[cc + 2][hr]; pk.h[3] = tbuf[cc + 3][hr];
        *(us4*)&OTb[(size_t)(h0 + hr) * 2048 + s0 + cc] = pk.v;
    }
}

// ---------------- GEMM1: Qf16 = tanh(Of16 * Wf16^T + bias) ----------------------
__global__ __launch_bounds__(256) void gemm1(const f16* __restrict__ A,
                                             const f16* __restrict__ W,
                                             const float* __restrict__ bias,
                                             f16* __restrict__ Qo) {
    __shared__ f16 lA[128 * 32];
    __shared__ f16 lB[128 * 32];
    const int tid = threadIdx.x;
    const int lane = tid & 63, w = tid >> 6;
    const int wm = w >> 1, wn = w & 1;
    const int bm = blockIdx.x >> 2, bn = blockIdx.x & 3;
    const int r0 = bm * 128, c0 = bn * 128;
    const int l15 = lane & 15, g = lane >> 4;
    f32x4 acc[4][4] = {};
    for (int kt = 0; kt < 16; ++kt) {
        int k0 = kt * 32;
        __syncthreads();
#pragma unroll
        for (int i = 0; i < 2; ++i) {
            int slot = i * 256 + tid;
            int row = slot >> 2, oct = slot & 3;
            int soct = oct ^ (row & 3);
            *(us8*)&lA[slot * 8] = *(const us8*)&A[(size_t)(r0 + row) * 512 + k0 + soct * 8];
            *(us8*)&lB[slot * 8] = *(const us8*)&W[(size_t)(c0 + row) * 512 + k0 + soct * 8];
        }
        __syncthreads();
        f16x8 af[4], bf[4];
#pragma unroll
        for (int mf = 0; mf < 4; ++mf) {
            int row = 64 * wm + 16 * mf + l15;
            int oct = g ^ (row & 3);
            af[mf] = *(const f16x8*)&lA[(row * 4 + oct) * 8];
        }
#pragma unroll
        for (int nf = 0; nf < 4; ++nf) {
            int row = 64 * wn + 16 * nf + l15;
            int oct = g ^ (row & 3);
            bf[nf] = *(const f16x8*)&lB[(row * 4 + oct) * 8];
        }
#pragma unroll
        for (int mf = 0; mf < 4; ++mf)
#pragma unroll
            for (int nf = 0; nf < 4; ++nf)
                acc[mf][nf] = MFMA16(af[mf], bf[nf], acc[mf][nf]);
    }
    float bv[4];
#pragma unroll
    for (int nf = 0; nf < 4; ++nf) bv[nf] = bias[c0 + 64 * wn + 16 * nf + l15];
#pragma unroll
    for (int mf = 0; mf < 4; ++mf) {
#pragma unroll
        for (int nf = 0; nf < 4; ++nf) {
#pragma unroll
            for (int r = 0; r < 4; ++r) {
                float y = tanhf(acc[mf][nf][r] + bv[nf]);
                int row = r0 + 64 * wm + 16 * mf + 4 * g + r;
                int col = c0 + 64 * wn + 16 * nf + l15;
                Qo[(size_t)row * 512 + col] = (f16)y;
            }
        }
    }
}

// ---------------- fused attention -----------------------------------------------
// Grid: 256 blocks. XCD decode: b = blk&7 (batch pinned to one XCD's L2), qt = blk>>3.
// Double-buffered K/V tiles staged via global_load_lds; counted vmcnt + raw barriers.
__global__ __launch_bounds__(256, 1) void attn(const f16* __restrict__ Qf,
                                               const f16* __restrict__ Of,
                                               const f16* __restrict__ OfT,
                                               float* __restrict__ Out) {
    extern __shared__ __align__(16) char smem[];  // 131072 bytes: 2 x {K 32KB, V 32KB}
    const int tid = threadIdx.x;
    const int lane = tid & 63, w = tid >> 6;
    const int l15 = lane & 15, g = lane >> 4;
    const int b = blockIdx.x & 7, qt = blockIdx.x >> 3;
    const int q0 = qt * 64;
    const f16* Ob  = Of  + (size_t)b * 2048 * 512;
    const f16* OTb = OfT + (size_t)b * 512 * 2048;

    // Q B-fragments in registers: q = q0 + 16w + l15, k = 32ks + 8g + j
    f16x8 qf[16];
    const f16* qrow = Qf + ((size_t)b * 2048 + q0 + 16 * w + l15) * 512;
#pragma unroll
    for (int ks = 0; ks < 16; ++ks) qf[ks] = *(const f16x8*)&qrow[ks * 32 + g * 8];

    float m = -INFINITY, lsum = 0.f;
    f32x4 acc[32] = {};

    const int addrA = 4 * (32 * (g & 1) + l15);
    const int addrB = addrA + 64;

    // ---- staging: 16 global_load_lds (dwordx4) per thread per tile ----
    auto STAGE = [&](int buf, int t0) {
        f16* lK = (f16*)(smem + buf * 65536);
        f16* lV = (f16*)(smem + buf * 65536 + 32768);
#pragma unroll
        for (int i = 0; i < 8; ++i) {
            int slot = i * 256 + tid;
            int t = slot >> 6, oct = slot & 63;
            gload_lds16(&Ob[(size_t)(t0 + t) * 512 + (oct ^ (t & 7)) * 8], &lK[slot * 8]);
        }
#pragma unroll
        for (int i = 0; i < 8; ++i) {
            int slot = i * 256 + tid;
            int h = slot >> 2, oct = slot & 3;
            gload_lds16(&OTb[(size_t)h * 2048 + t0 + (oct ^ (h & 3)) * 8], &lV[slot * 8]);
        }
    };

    STAGE(0, 0);
    STAGE(1, 32);

    for (int kt = 0; kt < 64; ++kt) {
        const int cur = kt & 1;
        // wait for current tile's 16 loads (leave next tile's 16 in flight)
        if (kt < 63) asm volatile("s_waitcnt vmcnt(16)" ::: "memory");
        else         asm volatile("s_waitcnt vmcnt(0)"  ::: "memory");
        __builtin_amdgcn_s_barrier();

        const f16* lK = (const f16*)(smem + cur * 65536);
        const f16* lV = (const f16*)(smem + cur * 65536 + 32768);

        // QK^T: S^T[t][q]
        f32x4 sa[2] = {};
#pragma unroll
        for (int ks = 0; ks < 16; ++ks) {
#pragma unroll
            for (int mf = 0; mf < 2; ++mf) {
                int t = 16 * mf + l15;
                int oct = (4 * ks + g) ^ (t & 7);
                f16x8 kf = *(const f16x8*)&lK[(t * 64 + oct) * 8];
                sa[mf] = MFMA16(kf, qf[ks], sa[mf]);
            }
        }

        // online softmax (defer-max THR=8)
        float tmax = -INFINITY;
#pragma unroll
        for (int mf = 0; mf < 2; ++mf)
#pragma unroll
            for (int r = 0; r < 4; ++r) tmax = fmaxf(tmax, sa[mf][r]);
        tmax = fmaxf(tmax, __shfl_xor(tmax, 16));
        tmax = fmaxf(tmax, __shfl_xor(tmax, 32));
        if (__any(tmax > m + 8.0f)) {
            float mnew = fmaxf(m, tmax);
            float corr = __expf(m - mnew);
            m = mnew;
            lsum *= corr;
#pragma unroll
            for (int hf = 0; hf < 32; ++hf) acc[hf] *= corr;
        }
        float p[2][4];
        float ps = 0.f;
#pragma unroll
        for (int mf = 0; mf < 2; ++mf)
#pragma unroll
            for (int r = 0; r < 4; ++r) { p[mf][r] = __expf(sa[mf][r] - m); ps += p[mf][r]; }
        ps += __shfl_xor(ps, 16);
        ps += __shfl_xor(ps, 32);
        lsum += ps;

        u32 Wd[2][2];
#pragma unroll
        for (int mf = 0; mf < 2; ++mf)
#pragma unroll
            for (int c = 0; c < 2; ++c) {
                union { f16 h[2]; u32 u; } x;
                x.h[0] = (f16)p[mf][2 * c]; x.h[1] = (f16)p[mf][2 * c + 1];
                Wd[mf][c] = x.u;
            }
        u32 word[4];
#pragma unroll
        for (int pp = 0; pp < 4; ++pp) {
            int adr = (pp >> 1) ? addrB : addrA;
            int w0 = __builtin_amdgcn_ds_bpermute(adr, (int)Wd[0][pp & 1]);
            int w1 = __builtin_amdgcn_ds_bpermute(adr, (int)Wd[1][pp & 1]);
            word[pp] = (lane >= 32) ? (u32)w1 : (u32)w0;
        }
        union { u32 u[4]; f16x8 v; } pkk;
        pkk.u[0] = word[0]; pkk.u[1] = word[1]; pkk.u[2] = word[2]; pkk.u[3] = word[3];
        f16x8 pfrag = pkk.v;

        // PV: D[h][q] += V^T[h][t] * P[q][t]
#pragma unroll
        for (int hf = 0; hf < 32; ++hf) {
            int h = 16 * hf + l15;
            int oct = g ^ (h & 3);
            f16x8 vf = *(const f16x8*)&lV[(h * 4 + oct) * 8];
            acc[hf] = MFMA16(vf, pfrag, acc[hf]);
        }

        __builtin_amdgcn_s_barrier();   // all waves done reading buf[cur]
        if (kt + 2 < 64) STAGE(cur, (kt + 2) * 32);
    }

    // epilogue: divide by lsum, transpose via LDS, store f32
    float inv = 1.0f / lsum;
#pragma unroll
    for (int hf = 0; hf < 32; ++hf) acc[hf] *= inv;

    float* lf = (float*)smem;  // [64 q][256 h] f32, h swizzled by ((q&7)<<2)
    const int q = 16 * w + l15;
#pragma unroll
    for (int half = 0; half < 2; ++half) {
        __syncthreads();
#pragma unroll
        for (int hfi = 0; hfi < 16; ++hfi) {
            int hf = 16 * half + hfi;
#pragma unroll
            for (int r = 0; r < 4; ++r) {
                int h = 16 * hf + 4 * g + r - half * 256;  // 0..255
                int hh = h ^ ((q & 7) << 2);
                lf[q * 256 + hh] = acc[hf][r];
            }
        }
        __syncthreads();
        int qr = tid >> 2;
        int c = tid & 3;
#pragma unroll
        for (int j = 0; j < 16; ++j) {
            int k4 = c + 4 * j;
            int hs = 4 * (k4 ^ (qr & 7));
            float4 vv = *(const float4*)&lf[qr * 256 + hs];
            *(float4*)&Out[((size_t)b * 2048 + q0 + qr) * 512 + half * 256 + 4 * k4] = vv;
        }
    }
}

extern "C" void kernel_launch(void* const* d_in, const int* in_sizes, int n_in,
                              void* d_out, int out_size, void* d_ws, size_t ws_size,
                              hipStream_t stream) {
    const float* O  = (const float*)d_in[0];
    const float* Ww = (const float*)d_in[1];
    const float* Wb = (const float*)d_in[2];
    float* Out = (float*)d_out;
    char* ws = (char*)d_ws;
    f16* Of16 = (f16*)ws;                           // 16 MB
    f16* OT   = (f16*)(ws + ((size_t)16 << 20));    // 16 MB
    f16* Qf   = (f16*)(ws + ((size_t)32 << 20));    // 16 MB
    f16* Wf   = (f16*)(ws + ((size_t)48 << 20));    // 512 KB

    hipFuncSetAttribute((const void*)attn, hipFuncAttributeMaxDynamicSharedMemorySize, 131072);

    castk<<<4096, 256, 0, stream>>>(O, Of16, 1048576);
    castk<<<128, 256, 0, stream>>>(Ww, Wf, 32768);
    transpose_cast<<<2048, 256, 0, stream>>>(O, OT);
    gemm1<<<512, 256, 0, stream>>>(Of16, Wf, Wb, Qf);
    attn<<<256, 256, 131072, stream>>>(Qf, Of16, OT, Out);
}